// Round 1
// baseline (153.430 us; speedup 1.0000x reference)
//
#include <hip/hip_runtime.h>

namespace {

constexpr int NQ      = 14;
constexpr int NSTATES = 1 << NQ;   // 16384
constexpr int DEPTH   = 3;
constexpr int BLOCK   = 1024;
constexpr int NWAVES  = BLOCK / 64;

__device__ __forceinline__ float2 cmul(float2 a, float2 b) {
    return make_float2(a.x * b.x - a.y * b.y, a.x * b.y + a.y * b.x);
}
__device__ __forceinline__ float2 cadd(float2 a, float2 b) {
    return make_float2(a.x + b.x, a.y + b.y);
}

__global__ __launch_bounds__(BLOCK) void qsim_kernel(
    const float* __restrict__ x,       // (batch, NQ)
    const float* __restrict__ prm,     // (DEPTH, NQ, 3)
    float* __restrict__ out)           // (batch, NQ)
{
    __shared__ float2 st[NSTATES];            // 128 KiB state
    __shared__ float  red[NWAVES][NQ];        // cross-wave reduction scratch

    const int b   = blockIdx.x;
    const int tid = threadIdx.x;

    // |0...0>
    for (int i = tid; i < NSTATES; i += BLOCK) st[i] = make_float2(0.f, 0.f);
    if (tid == 0) st[0] = make_float2(1.f, 0.f);
    __syncthreads();

    for (int l = 0; l < DEPTH; ++l) {
        // ---- fused single-qubit rotations: U = RZ(az)·RY(ay)·RX(ax [+x_q if l==0]) ----
        for (int q = 0; q < NQ; ++q) {
            float ax = prm[(l * NQ + q) * 3 + 0] + (l == 0 ? x[b * NQ + q] : 0.f);
            float ay = prm[(l * NQ + q) * 3 + 1];
            float az = prm[(l * NQ + q) * 3 + 2];
            float cx, sx, cy, sy, cz, sz;
            sincosf(0.5f * ax, &sx, &cx);
            sincosf(0.5f * ay, &sy, &cy);
            sincosf(0.5f * az, &sz, &cz);

            // M = RY·RX
            float2 M00 = make_float2( cy * cx,  sy * sx);
            float2 M01 = make_float2(-sy * cx, -cy * sx);
            float2 M10 = make_float2( sy * cx, -cy * sx);
            float2 M11 = make_float2( cy * cx, -sy * sx);
            // U = RZ·M : row0 *= e^{-i az/2}, row1 *= e^{+i az/2}
            float2 ez  = make_float2(cz, -sz);
            float2 ezc = make_float2(cz,  sz);
            float2 U00 = cmul(ez,  M00);
            float2 U01 = cmul(ez,  M01);
            float2 U10 = cmul(ezc, M10);
            float2 U11 = cmul(ezc, M11);

            const int m  = 1 << (NQ - 1 - q);
            const int ml = m - 1;
            for (int k = tid; k < NSTATES / 2; k += BLOCK) {
                int i0 = ((k & ~ml) << 1) | (k & ml);
                int i1 = i0 | m;
                float2 a0 = st[i0];
                float2 a1 = st[i1];
                float2 n0 = cadd(cmul(U00, a0), cmul(U01, a1));
                float2 n1 = cadd(cmul(U10, a0), cmul(U11, a1));
                st[i0] = n0;
                st[i1] = n1;
            }
            __syncthreads();
        }

        // ---- CNOT ring: (0,1),(1,2),...,(12,13),(13,0) ----
        for (int e = 0; e < NQ; ++e) {
            const int c = (e == NQ - 1) ? NQ - 1 : e;
            const int t = (e == NQ - 1) ? 0      : e + 1;
            const int pc = NQ - 1 - c;
            const int pt = NQ - 1 - t;
            const int pl = pc < pt ? pc : pt;
            const int ph = pc < pt ? pt : pc;
            const int mlo = (1 << pl) - 1;
            const int mhi = (1 << ph) - 1;
            const int mc = 1 << pc;
            const int mt = 1 << pt;

            for (int k = tid; k < NSTATES / 4; k += BLOCK) {
                int v = k;
                v = ((v & ~mlo) << 1) | (v & mlo);   // insert 0 at pl
                v = ((v & ~mhi) << 1) | (v & mhi);   // insert 0 at ph
                int i = v | mc;                       // control = 1, target = 0
                int j = i | mt;                       // control = 1, target = 1
                float2 a = st[i];
                float2 bv = st[j];
                st[i] = bv;
                st[j] = a;
            }
            __syncthreads();
        }
    }

    // ---- expectation values <Z_w> = sum_i p_i * (1 - 2*bit_w(i)) ----
    float acc[NQ];
#pragma unroll
    for (int w = 0; w < NQ; ++w) acc[w] = 0.f;

    for (int i = tid; i < NSTATES; i += BLOCK) {
        float2 a = st[i];
        float p = a.x * a.x + a.y * a.y;
#pragma unroll
        for (int w = 0; w < NQ; ++w) {
            acc[w] += ((i >> (NQ - 1 - w)) & 1) ? -p : p;
        }
    }

    const int lane = tid & 63;
    const int wave = tid >> 6;
#pragma unroll
    for (int w = 0; w < NQ; ++w) {
        float v = acc[w];
#pragma unroll
        for (int off = 32; off > 0; off >>= 1) v += __shfl_down(v, off, 64);
        if (lane == 0) red[wave][w] = v;
    }
    __syncthreads();

    if (tid < NQ) {
        float s = 0.f;
#pragma unroll
        for (int wv = 0; wv < NWAVES; ++wv) s += red[wv][tid];
        out[b * NQ + tid] = s;
    }
}

}  // namespace

extern "C" void kernel_launch(void* const* d_in, const int* in_sizes, int n_in,
                              void* d_out, int out_size, void* d_ws, size_t ws_size,
                              hipStream_t stream) {
    const float* x   = (const float*)d_in[0];   // (batch, 14) f32
    const float* prm = (const float*)d_in[1];   // (3, 14, 3) f32
    float* out = (float*)d_out;                 // (batch, 14) f32
    const int batch = in_sizes[0] / NQ;
    qsim_kernel<<<batch, BLOCK, 0, stream>>>(x, prm, out);
}

// Round 2
// 53.805 us; speedup vs baseline: 2.8516x; 2.8516x over previous
//
#include <hip/hip_runtime.h>

namespace {

constexpr int NQ      = 14;
constexpr int NSTATES = 1 << NQ;   // 16384
constexpr int DEPTH   = 3;
constexpr int BLOCK   = 1024;
constexpr int NWAVES  = BLOCK / 64;
constexpr int NQUADS  = NSTATES / 4;          // 4096
constexpr int QPT     = NQUADS / BLOCK;       // 4 quads per thread per pass

// ---------- compile-time GF(2) machinery for deferred CNOTs ----------
constexpr int cmsb(unsigned x) { int m = -1; for (int i = 0; i < 16; ++i) if ((x >> i) & 1) m = i; return m; }
constexpr unsigned cparity(unsigned x) { x ^= x >> 8; x ^= x >> 4; x ^= x >> 2; x ^= x >> 1; return x & 1u; }

struct Mat { unsigned row[NQ]; unsigned col[NQ]; };

// M after `nrings` CNOT-ring layers. stored[s] = amp[M s].
// CNOT(c,t): M' = C*M (row_Pt ^= row_Pc), Minv' = Minv*C (col_Pc ^= col_Pt).
constexpr Mat m_after(int nrings) {
  Mat m{};
  for (int p = 0; p < NQ; ++p) { m.row[p] = 1u << p; m.col[p] = 1u << p; }
  for (int l = 0; l < nrings; ++l) {
    for (int q = 0; q < NQ; ++q) {
      int cq = (q == NQ - 1) ? NQ - 1 : q;
      int tq = (q == NQ - 1) ? 0 : q + 1;
      int Pc = NQ - 1 - cq, Pt = NQ - 1 - tq;
      m.row[Pt] ^= m.row[Pc];
      m.col[Pc] ^= m.col[Pt];
    }
  }
  return m;
}

struct PassCfg {
  unsigned da, db, dab;   // XOR offsets for gate A (qubit 2J) and B (qubit 2J+1)
  int p_hi, p_lo;         // RREF pivot bit positions of the parity constraints
  unsigned m1, m2;        // fill-parity masks for bits p_hi / p_lo
  unsigned lo_mask, hi_mask;
};

// Pass for layer L, qubit pair (2J, 2J+1). Enumerates the representative s0
// with physical parities pa=pb=0 directly: insert zeros at pivots, fill pivot
// bits from parity constraints. Quad = {s0, s0^da, s0^db, s0^da^db} with
// STATIC matrix roles.
constexpr PassCfg make_cfg(int L, int J) {
  Mat m = m_after(L);
  int qa = 2 * J, qb = 2 * J + 1;
  unsigned da = m.col[NQ - 1 - qa], db = m.col[NQ - 1 - qb];
  unsigned r1 = m.row[NQ - 1 - qa], r2 = m.row[NQ - 1 - qb];
  if (cmsb(r2) > cmsb(r1)) { unsigned t = r1; r1 = r2; r2 = t; }
  int p1 = cmsb(r1);
  if ((r2 >> p1) & 1) r2 ^= r1;
  int p2 = cmsb(r2);
  if ((r1 >> p2) & 1) r1 ^= r2;
  PassCfg c{};
  c.da = da; c.db = db; c.dab = da ^ db;
  c.p_hi = p1; c.p_lo = p2;
  c.m1 = r1 & ~(1u << p1);
  c.m2 = r2 & ~(1u << p2);
  c.lo_mask = (1u << p2) - 1u;
  c.hi_mask = (1u << p1) - 1u;
  return c;
}

constexpr Mat MFIN = m_after(DEPTH);

// LDS layout swizzle (bijective, linear): spreads strided patterns over banks.
constexpr unsigned cslot(unsigned i) { return i ^ ((i >> 2) & 31u); }
__device__ __forceinline__ unsigned slot_of(unsigned i) { return i ^ ((i >> 2) & 31u); }

__device__ __forceinline__ float2 cmul(float2 a, float2 b) {
  return make_float2(a.x * b.x - a.y * b.y, a.x * b.y + a.y * b.x);
}
__device__ __forceinline__ float2 cfma(float2 a, float2 b, float2 c) {  // c + a*b
  return make_float2(fmaf(a.x, b.x, fmaf(-a.y, b.y, c.x)),
                     fmaf(a.x, b.y, fmaf(a.y, b.x, c.y)));
}

template <int L, int J>
__device__ __forceinline__ void do_pass(float2* __restrict__ st,
                                        const float2* __restrict__ Utab, int tid) {
  constexpr PassCfg c = make_cfg(L, J);
  constexpr unsigned sda  = cslot(c.da)  ^ 0u;   // slot(i^d) = slot(i) ^ cslot(d)
  constexpr unsigned sdb  = cslot(c.db);
  constexpr unsigned sdab = cslot(c.dab);

  const float2* Ua = &Utab[(L * NQ + 2 * J) * 4];
  const float2* Ub = &Utab[(L * NQ + 2 * J + 1) * 4];
  float2 A00 = Ua[0], A01 = Ua[1], A10 = Ua[2], A11 = Ua[3];
  float2 B00 = Ub[0], B01 = Ub[1], B10 = Ub[2], B11 = Ub[3];

#pragma unroll 2
  for (int jq = 0; jq < QPT; ++jq) {
    unsigned k = (unsigned)tid + (unsigned)jq * BLOCK;
    unsigned e = ((k & ~c.lo_mask) << 1) | (k & c.lo_mask);
    e = ((e & ~c.hi_mask) << 1) | (e & c.hi_mask);
    unsigned f1 = __popc(e & c.m1) & 1u;
    unsigned f2 = __popc(e & c.m2) & 1u;
    unsigned s0 = e | (f1 << c.p_hi) | (f2 << c.p_lo);
    unsigned sl = slot_of(s0);

    float2 a00 = st[sl];
    float2 a10 = st[sl ^ sda];
    float2 a01 = st[sl ^ sdb];
    float2 a11 = st[sl ^ sdab];

    // gate A along da (row index = physical parity pa)
    float2 t00 = cfma(A01, a10, cmul(A00, a00));
    float2 t10 = cfma(A11, a10, cmul(A10, a00));
    float2 t01 = cfma(A01, a11, cmul(A00, a01));
    float2 t11 = cfma(A11, a11, cmul(A10, a01));
    // gate B along db
    float2 n00 = cfma(B01, t01, cmul(B00, t00));
    float2 n01 = cfma(B11, t01, cmul(B10, t00));
    float2 n10 = cfma(B01, t11, cmul(B00, t10));
    float2 n11 = cfma(B11, t11, cmul(B10, t10));

    st[sl]        = n00;
    st[sl ^ sda]  = n10;
    st[sl ^ sdb]  = n01;
    st[sl ^ sdab] = n11;
  }
}

__global__ __launch_bounds__(BLOCK) void qsim_kernel(
    const float* __restrict__ x,     // (batch, NQ)
    const float* __restrict__ prm,   // (DEPTH, NQ, 3)
    float* __restrict__ out)         // (batch, NQ)
{
  __shared__ float2 st[NSTATES];                 // 128 KiB
  __shared__ float2 Utab[DEPTH * NQ * 4];        // 42 gate matrices
  __shared__ float  red[NWAVES][NQ];

  const int b   = blockIdx.x;
  const int tid = threadIdx.x;

  // init |0...0>  (slot(0)==0)
  for (int i = tid; i < NSTATES; i += BLOCK) st[i] = make_float2(0.f, 0.f);
  if (tid == 0) st[0] = make_float2(1.f, 0.f);

  // build all 42 fused RZ*RY*RX matrices (x folded into layer-0 RX angle)
  if (tid < DEPTH * NQ) {
    int l = tid / NQ, q = tid % NQ;
    float ax = prm[(l * NQ + q) * 3 + 0] + (l == 0 ? x[b * NQ + q] : 0.f);
    float ay = prm[(l * NQ + q) * 3 + 1];
    float az = prm[(l * NQ + q) * 3 + 2];
    float cx, sx, cy, sy, cz, sz;
    sincosf(0.5f * ax, &sx, &cx);
    sincosf(0.5f * ay, &sy, &cy);
    sincosf(0.5f * az, &sz, &cz);
    float2 M00 = make_float2( cy * cx,  sy * sx);
    float2 M01 = make_float2(-sy * cx, -cy * sx);
    float2 M10 = make_float2( sy * cx, -cy * sx);
    float2 M11 = make_float2( cy * cx, -sy * sx);
    float2 ez  = make_float2(cz, -sz);
    float2 ezc = make_float2(cz,  sz);
    float2* U = &Utab[tid * 4];
    U[0] = cmul(ez,  M00);
    U[1] = cmul(ez,  M01);
    U[2] = cmul(ezc, M10);
    U[3] = cmul(ezc, M11);
  }
  __syncthreads();

#define PASS(L, J) do_pass<L, J>(st, Utab, tid); __syncthreads();
  PASS(0,0) PASS(0,1) PASS(0,2) PASS(0,3) PASS(0,4) PASS(0,5) PASS(0,6)
  PASS(1,0) PASS(1,1) PASS(1,2) PASS(1,3) PASS(1,4) PASS(1,5) PASS(1,6)
  PASS(2,0) PASS(2,1) PASS(2,2) PASS(2,3) PASS(2,4) PASS(2,5) PASS(2,6)
#undef PASS

  // ---- expectations: <Z_w> = sum_i p_i * (-1)^parity(rowfin_w & i) ----
  // sign factors: parity(r & (tid | j<<10)) = parity(r & tid) ^ parity(r & j<<10)
  float acc[NQ];
#pragma unroll
  for (int w = 0; w < NQ; ++w) acc[w] = 0.f;

#pragma unroll
  for (int j = 0; j < NSTATES / BLOCK; ++j) {
    unsigned i = (unsigned)tid | ((unsigned)j << 10);
    float2 a = st[slot_of(i)];
    float p = a.x * a.x + a.y * a.y;
#pragma unroll
    for (int w = 0; w < NQ; ++w) {
      if (cparity(MFIN.row[NQ - 1 - w] & ((unsigned)j << 10))) acc[w] -= p;
      else                                                      acc[w] += p;
    }
  }

  const int lane = tid & 63;
  const int wave = tid >> 6;
#pragma unroll
  for (int w = 0; w < NQ; ++w) {
    unsigned pw = __popc(MFIN.row[NQ - 1 - w] & (unsigned)tid) & 1u;
    float v = pw ? -acc[w] : acc[w];
#pragma unroll
    for (int off = 32; off > 0; off >>= 1) v += __shfl_down(v, off, 64);
    if (lane == 0) red[wave][w] = v;
  }
  __syncthreads();

  if (tid < NQ) {
    float s = 0.f;
#pragma unroll
    for (int wv = 0; wv < NWAVES; ++wv) s += red[wv][tid];
    out[b * NQ + tid] = s;
  }
}

}  // namespace

extern "C" void kernel_launch(void* const* d_in, const int* in_sizes, int n_in,
                              void* d_out, int out_size, void* d_ws, size_t ws_size,
                              hipStream_t stream) {
  const float* x   = (const float*)d_in[0];   // (batch, 14) f32
  const float* prm = (const float*)d_in[1];   // (3, 14, 3) f32
  float* out = (float*)d_out;                 // (batch, 14) f32
  const int batch = in_sizes[0] / NQ;
  qsim_kernel<<<batch, BLOCK, 0, stream>>>(x, prm, out);
}

// Round 3
// 43.634 us; speedup vs baseline: 3.5163x; 1.2331x over previous
//
#include <hip/hip_runtime.h>

namespace {

using v2f = __attribute__((ext_vector_type(2))) float;

constexpr int NQ      = 14;
constexpr int NSTATES = 1 << NQ;   // 16384
constexpr int DEPTH   = 3;
constexpr int BLOCK   = 1024;
constexpr int NWAVES  = BLOCK / 64;

// ---------- compile-time GF(2) machinery for deferred CNOTs ----------
constexpr int cmsb(unsigned x) { int m = -1; for (int i = 0; i < 16; ++i) if ((x >> i) & 1) m = i; return m; }
constexpr unsigned cparity(unsigned x) { x ^= x >> 8; x ^= x >> 4; x ^= x >> 2; x ^= x >> 1; return x & 1u; }

struct Mat { unsigned row[NQ]; unsigned col[NQ]; };

// M after `nrings` CNOT-ring layers. stored[s] = amp[M s].
constexpr Mat m_after(int nrings) {
  Mat m{};
  for (int p = 0; p < NQ; ++p) { m.row[p] = 1u << p; m.col[p] = 1u << p; }
  for (int l = 0; l < nrings; ++l) {
    for (int q = 0; q < NQ; ++q) {
      int cq = (q == NQ - 1) ? NQ - 1 : q;
      int tq = (q == NQ - 1) ? 0 : q + 1;
      int Pc = NQ - 1 - cq, Pt = NQ - 1 - tq;
      m.row[Pt] ^= m.row[Pc];
      m.col[Pc] ^= m.col[Pt];
    }
  }
  return m;
}

constexpr Mat MFIN = m_after(DEPTH);

// LDS layout swizzle (bijective, XOR-linear): slot(i^d) = slot(i) ^ cslot(d)
constexpr unsigned cslot(unsigned i) { return i ^ ((i >> 2) & 31u); }

// ---- group-of-G gate pass config: coset generators + RREF of parity rows ----
template <int G>
struct GCfg {
  unsigned cs[1 << G];   // cslot() of XOR-combination v of the G masks
  int      piv[G];       // RREF pivot bit positions, ascending
  unsigned fm[G];        // fill-parity masks per pivot (no pivot bits inside)
  unsigned ins[G];       // (1<<piv)-1 insertion masks
};

template <int G>
constexpr GCfg<G> make_gcfg(int L, int Q0) {
  Mat m = m_after(L);
  GCfg<G> c{};
  unsigned d[G] = {};
  unsigned r[G] = {};
  for (int g = 0; g < G; ++g) {
    d[g] = m.col[NQ - 1 - (Q0 + g)];
    r[g] = m.row[NQ - 1 - (Q0 + g)];
  }
  for (int v = 0; v < (1 << G); ++v) {
    unsigned D = 0;
    for (int g = 0; g < G; ++g) if ((v >> g) & 1) D ^= d[g];
    c.cs[v] = cslot(D);
  }
  // RREF: unique pivot per row, eliminated from all other rows
  int piv[G] = {};
  for (int i = 0; i < G; ++i) {
    int best = i;
    for (int j = i + 1; j < G; ++j) if (cmsb(r[j]) > cmsb(r[best])) best = j;
    unsigned t = r[i]; r[i] = r[best]; r[best] = t;
    piv[i] = cmsb(r[i]);
    for (int j = 0; j < G; ++j) if (j != i && ((r[j] >> piv[i]) & 1)) r[j] ^= r[i];
  }
  // sort by pivot ascending (insertion order)
  for (int i = 0; i < G; ++i)
    for (int j = i + 1; j < G; ++j)
      if (piv[j] < piv[i]) {
        int tp = piv[i]; piv[i] = piv[j]; piv[j] = tp;
        unsigned tr = r[i]; r[i] = r[j]; r[j] = tr;
      }
  for (int g = 0; g < G; ++g) {
    c.piv[g] = piv[g];
    c.fm[g]  = r[g] & ~(1u << piv[g]);
    c.ins[g] = (1u << piv[g]) - 1u;
  }
  return c;
}

// ---------- packed-f32 complex helpers ----------
__device__ __forceinline__ v2f mkv(float a, float b) { v2f r; r[0] = a; r[1] = b; return r; }

__device__ __forceinline__ v2f pk_mul(v2f a, v2f b) {
  v2f d;
  asm("v_pk_mul_f32 %0, %1, %2 op_sel:[0,0] op_sel_hi:[1,1]" : "=v"(d) : "v"(a), "v"(b));
  return d;
}
__device__ __forceinline__ v2f pk_fma(v2f a, v2f b, v2f c) {
  v2f d;
  asm("v_pk_fma_f32 %0, %1, %2, %3 op_sel:[0,0,0] op_sel_hi:[1,1,1]" : "=v"(d) : "v"(a), "v"(b), "v"(c));
  return d;
}
// d.lo = fma(a.lo, b.hi, c.lo) ; d.hi = fma(a.hi, b.lo, c.hi)   (src1 halves swapped)
__device__ __forceinline__ v2f pk_fma_swap1(v2f a, v2f b, v2f c) {
  v2f d;
  asm("v_pk_fma_f32 %0, %1, %2, %3 op_sel:[0,1,0] op_sel_hi:[1,0,1]" : "=v"(d) : "v"(a), "v"(b), "v"(c));
  return d;
}
// complex (x+iy)*s with uxx=(x,x), uyn=(-y,y):  2 packed instrs
__device__ __forceinline__ v2f cmul_pk(v2f uxx, v2f uyn, v2f s) {
  return pk_fma_swap1(uyn, s, pk_mul(uxx, s));
}
__device__ __forceinline__ v2f cfma_pk(v2f uxx, v2f uyn, v2f s, v2f acc) {
  return pk_fma_swap1(uyn, s, pk_fma(uxx, s, acc));
}

__device__ __forceinline__ float2 cmulf(float2 a, float2 b) {
  return make_float2(a.x * b.x - a.y * b.y, a.x * b.y + a.y * b.x);
}

// ---------- one pass: G gates applied to a 2^G XOR-coset in registers ----------
template <int L, int Q0, int G>
__device__ __forceinline__ void do_pass(v2f* __restrict__ st,
                                        const v2f* __restrict__ Upk, int tid) {
  constexpr GCfg<G> c = make_gcfg<G>(L, Q0);
  constexpr int NC   = 1 << G;
  constexpr int ITER = NSTATES / NC / BLOCK;

#pragma unroll
  for (int it = 0; it < ITER; ++it) {
    unsigned k = (unsigned)tid + (unsigned)it * BLOCK;
    unsigned e = k;
#pragma unroll
    for (int g = 0; g < G; ++g) e = ((e & ~c.ins[g]) << 1) | (e & c.ins[g]);
    unsigned s0 = e;
#pragma unroll
    for (int g = 0; g < G; ++g) s0 |= (unsigned)(__popc(e & c.fm[g]) & 1) << c.piv[g];
    unsigned sl = s0 ^ ((s0 >> 2) & 31u);

    v2f a[NC];
#pragma unroll
    for (int v = 0; v < NC; ++v) a[v] = st[sl ^ c.cs[v]];

#pragma unroll
    for (int g = 0; g < G; ++g) {
      const v2f* Ug = &Upk[(L * NQ + Q0 + g) * 8];
      v2f u00x = Ug[0], u00n = Ug[1], u01x = Ug[2], u01n = Ug[3];
      v2f u10x = Ug[4], u10n = Ug[5], u11x = Ug[6], u11n = Ug[7];
#pragma unroll
      for (int v = 0; v < NC; ++v) {
        if (!((v >> g) & 1)) {
          int w = v | (1 << g);
          v2f a0 = a[v], a1 = a[w];
          a[v] = cfma_pk(u01x, u01n, a1, cmul_pk(u00x, u00n, a0));
          a[w] = cfma_pk(u11x, u11n, a1, cmul_pk(u10x, u10n, a0));
        }
      }
    }

#pragma unroll
    for (int v = 0; v < NC; ++v) st[sl ^ c.cs[v]] = a[v];
  }
}

__global__ __launch_bounds__(BLOCK) void qsim_kernel(
    const float* __restrict__ x,     // (batch, NQ)
    const float* __restrict__ prm,   // (DEPTH, NQ, 3)
    float* __restrict__ out)         // (batch, NQ)
{
  __shared__ v2f   st[NSTATES];                 // 128 KiB state
  __shared__ v2f   Upk[DEPTH * NQ * 8];         // pre-packed gate constants
  __shared__ float red[NWAVES][NQ];

  const int b   = blockIdx.x;
  const int tid = threadIdx.x;

  for (int i = tid; i < NSTATES; i += BLOCK) st[i] = mkv(0.f, 0.f);
  if (tid == 0) st[0] = mkv(1.f, 0.f);

  // build all 42 fused RZ*RY*RX matrices, pre-packed as (x,x),(-y,y) per entry
  if (tid < DEPTH * NQ) {
    int l = tid / NQ, q = tid % NQ;
    float ax = prm[(l * NQ + q) * 3 + 0] + (l == 0 ? x[b * NQ + q] : 0.f);
    float ay = prm[(l * NQ + q) * 3 + 1];
    float az = prm[(l * NQ + q) * 3 + 2];
    float cx, sx, cy, sy, cz, sz;
    sincosf(0.5f * ax, &sx, &cx);
    sincosf(0.5f * ay, &sy, &cy);
    sincosf(0.5f * az, &sz, &cz);
    float2 M00 = make_float2( cy * cx,  sy * sx);
    float2 M01 = make_float2(-sy * cx, -cy * sx);
    float2 M10 = make_float2( sy * cx, -cy * sx);
    float2 M11 = make_float2( cy * cx, -sy * sx);
    float2 ez  = make_float2(cz, -sz);
    float2 ezc = make_float2(cz,  sz);
    float2 U00 = cmulf(ez,  M00);
    float2 U01 = cmulf(ez,  M01);
    float2 U10 = cmulf(ezc, M10);
    float2 U11 = cmulf(ezc, M11);
    v2f* U = &Upk[tid * 8];
    U[0] = mkv(U00.x, U00.x); U[1] = mkv(-U00.y, U00.y);
    U[2] = mkv(U01.x, U01.x); U[3] = mkv(-U01.y, U01.y);
    U[4] = mkv(U10.x, U10.x); U[5] = mkv(-U10.y, U10.y);
    U[6] = mkv(U11.x, U11.x); U[7] = mkv(-U11.y, U11.y);
  }
  __syncthreads();

#define PASS(L, Q0, G) do_pass<L, Q0, G>(st, Upk, tid); __syncthreads();
  PASS(0, 0, 4) PASS(0, 4, 4) PASS(0, 8, 4) PASS(0, 12, 2)
  PASS(1, 0, 4) PASS(1, 4, 4) PASS(1, 8, 4) PASS(1, 12, 2)
  PASS(2, 0, 4) PASS(2, 4, 4) PASS(2, 8, 4) PASS(2, 12, 2)
#undef PASS

  // ---- expectations: <Z_w> = sum_i p_i * (-1)^parity(rowfin_w & i) ----
  float acc[NQ];
#pragma unroll
  for (int w = 0; w < NQ; ++w) acc[w] = 0.f;

#pragma unroll
  for (int j = 0; j < NSTATES / BLOCK; ++j) {
    unsigned i = (unsigned)tid | ((unsigned)j << 10);
    v2f a = st[i ^ ((i >> 2) & 31u)];
    float p = a[0] * a[0] + a[1] * a[1];
#pragma unroll
    for (int w = 0; w < NQ; ++w) {
      if (cparity(MFIN.row[NQ - 1 - w] & ((unsigned)j << 10))) acc[w] -= p;
      else                                                      acc[w] += p;
    }
  }

  const int lane = tid & 63;
  const int wave = tid >> 6;
#pragma unroll
  for (int w = 0; w < NQ; ++w) {
    unsigned pw = __popc(MFIN.row[NQ - 1 - w] & (unsigned)tid) & 1u;
    float v = pw ? -acc[w] : acc[w];
#pragma unroll
    for (int off = 32; off > 0; off >>= 1) v += __shfl_down(v, off, 64);
    if (lane == 0) red[wave][w] = v;
  }
  __syncthreads();

  if (tid < NQ) {
    float s = 0.f;
#pragma unroll
    for (int wv = 0; wv < NWAVES; ++wv) s += red[wv][tid];
    out[b * NQ + tid] = s;
  }
}

}  // namespace

extern "C" void kernel_launch(void* const* d_in, const int* in_sizes, int n_in,
                              void* d_out, int out_size, void* d_ws, size_t ws_size,
                              hipStream_t stream) {
  const float* x   = (const float*)d_in[0];   // (batch, 14) f32
  const float* prm = (const float*)d_in[1];   // (3, 14, 3) f32
  float* out = (float*)d_out;                 // (batch, 14) f32
  const int batch = in_sizes[0] / NQ;
  qsim_kernel<<<batch, BLOCK, 0, stream>>>(x, prm, out);
}

// Round 4
// 42.586 us; speedup vs baseline: 3.6028x; 1.0246x over previous
//
#include <hip/hip_runtime.h>

namespace {

using v2f = __attribute__((ext_vector_type(2))) float;

constexpr int NQ      = 14;
constexpr int NSTATES = 1 << NQ;
constexpr int BLOCK   = 1024;
constexpr int NWAVES  = BLOCK / 64;

// ---------------- compile-time GF(2) machinery ----------------
constexpr unsigned cparity(unsigned x){ x^=x>>8; x^=x>>4; x^=x>>2; x^=x>>1; return x&1u; }

struct Mat { unsigned row[NQ]; unsigned col[NQ]; };

constexpr Mat m_after(int nr){
  Mat m{};
  for(int p=0;p<NQ;++p){ m.row[p]=1u<<p; m.col[p]=1u<<p; }
  for(int l=0;l<nr;++l)
    for(int q=0;q<NQ;++q){
      int cq=(q==NQ-1)?NQ-1:q, tq=(q==NQ-1)?0:q+1;
      int Pc=NQ-1-cq, Pt=NQ-1-tq;
      m.row[Pt]^=m.row[Pc]; m.col[Pc]^=m.col[Pt];
    }
  return m;
}

constexpr Mat M1=m_after(1), M2=m_after(2), M3=m_after(3);
constexpr unsigned amask(int q){ return M1.col[NQ-1-q]; }
constexpr unsigned arow (int q){ return M1.row[NQ-1-q]; }
constexpr unsigned bmask(int q){ return M2.col[NQ-1-q]; }
constexpr unsigned brow (int q){ return M2.row[NQ-1-q]; }

constexpr int rank_of(const unsigned* v, int n){
  unsigned a[24]{};
  for(int i=0;i<n;++i) a[i]=v[i];
  int r=0;
  for(int bit=15;bit>=0;--bit){
    int p=-1;
    for(int i=r;i<n;++i){ if((a[i]>>bit)&1){ p=i; break; } }
    if(p<0) continue;
    unsigned t=a[r]; a[r]=a[p]; a[p]=t;
    for(int i=0;i<n;++i) if(i!=r && ((a[i]>>bit)&1)) a[i]^=a[r];
    ++r;
  }
  return r;
}

constexpr unsigned swzf(unsigned s, int k){ return s ^ ((s>>k)&31u); }

constexpr int proj_rank4(const unsigned* cols, int n, int k){
  unsigned a[8]{};
  for(int i=0;i<n;++i) a[i]=swzf(cols[i],k)&15u;
  int r=0;
  for(int bit=3;bit>=0;--bit){
    int p=-1;
    for(int i=r;i<n;++i){ if((a[i]>>bit)&1){ p=i; break; } }
    if(p<0) continue;
    unsigned t=a[r]; a[r]=a[p]; a[p]=t;
    for(int i=0;i<n;++i) if(i!=r && ((a[i]>>bit)&1)) a[i]^=a[r];
    ++r;
  }
  return r;
}

struct Plan {
  unsigned A[14], B[14], C[14];
  int BlaneGi[6]; unsigned BlanePi4[6];
  int BregGi[4];  unsigned BregEps[4];
  int CregGi[4];  unsigned CregEps[4];
  int ClaneGi[4]; unsigned ClaneEps[4];
  unsigned EJ4[14], ET[14];
  int K;
  unsigned SA[16], SB[16], SC[16];
  unsigned TA[10], TB[10], TCc[10];
};

constexpr Plan make_plan(){
  Plan P{};
  // Phase A: all columns = layer-1 Minv columns; j:q0..3, lane:q4..9, wave:q10..13
  for(int t=0;t<14;++t) P.A[t]=amask(t);
  // Phase B: j cols = layer-1 leftover masks (q10..13); greedy-extend with layer-2 masks
  for(int t=0;t<4;++t){ P.B[t]=amask(10+t); P.BregGi[t]=10+t; }
  bool used[14]{}; int picked[14]{}; int np=0;
  {
    unsigned cur[20]{}; int nc=0;
    for(int t=0;t<4;++t) cur[nc++]=P.B[t];
    for(int q=0;q<14 && np<10;++q){
      cur[nc]=bmask(q);
      if(rank_of(cur,nc+1)==nc+1){ ++nc; picked[np++]=q; used[q]=true; }
    }
  }
  for(int i=0;i<6;++i){ P.B[4+i]=bmask(picked[i]); P.BlaneGi[i]=14+picked[i]; }
  int wq[4]{}, un[4]{}; int nu=0;
  for(int i=0;i<4;++i){ wq[i]=picked[6+i]; P.B[10+i]=bmask(wq[i]); P.CregGi[i]=14+wq[i]; }
  for(int q=0;q<14;++q) if(!used[q]) un[nu++]=q;
  for(int i=0;i<4;++i) P.ClaneGi[i]=14+un[i];
  // eps / pi masks for phase B
  for(int i=0;i<4;++i){ unsigned m=0;
    for(int t=0;t<10;++t) m |= cparity(arow(10+i)&P.B[4+t])<<t;
    P.BregEps[i]=m; }
  for(int i=0;i<6;++i){ unsigned m=0;
    for(int t=0;t<4;++t) m |= cparity(brow(picked[i])&P.B[t])<<t;
    P.BlanePi4[i]=m; }
  // Phase C cols: j = wq masks, lane gates = un masks, completions = unit vectors
  for(int t=0;t<4;++t) P.C[t]=bmask(wq[t]);
  for(int t=0;t<4;++t) P.C[4+t]=bmask(un[t]);
  {
    unsigned cc[20]{}; int n=0;
    for(int t=0;t<8;++t) cc[n++]=P.C[t];
    int pos=8;
    for(int p=0;p<14 && pos<14;++p){
      cc[n]=1u<<p;
      if(rank_of(cc,n+1)==n+1){ P.C[pos]=1u<<p; ++n; ++pos; }
    }
  }
  for(int i=0;i<4;++i){ unsigned m=0;
    for(int t=0;t<10;++t) m |= cparity(brow(wq[i])&P.C[4+t])<<t;
    P.CregEps[i]=m; }
  for(int i=0;i<4;++i){ unsigned m=0;
    for(int t=0;t<10;++t){ if(t==i) continue; m |= cparity(brow(un[i])&P.C[4+t])<<t; }
    P.ClaneEps[i]=m; }
  // expectation signs from final map (phase C)
  for(int w=0;w<14;++w){
    unsigned R=M3.row[NQ-1-w]; unsigned mj=0, mt=0;
    for(int t=0;t<4;++t)  mj |= cparity(R&P.C[t])<<t;
    for(int t=0;t<10;++t) mt |= cparity(R&P.C[4+t])<<t;
    P.EJ4[w]=mj; P.ET[w]=mt;
  }
  // swizzle selection by bank-balance rank
  int bestk=2, bests=-1;
  for(int k=2;k<=9;++k){
    unsigned ini[6]={16,32,64,128,256,512};
    int s = proj_rank4(ini,6,k) + proj_rank4(&P.A[4],6,k)
          + proj_rank4(&P.B[4],6,k) + proj_rank4(&P.C[4],6,k);
    if(s>bests){ bests=s; bestk=k; }
  }
  P.K=bestk;
  for(int j=0;j<16;++j){
    unsigned sa=0, sb=0, sc=0;
    for(int t=0;t<4;++t) if((j>>t)&1){ sa^=P.A[t]; sb^=P.B[t]; sc^=P.C[t]; }
    P.SA[j]=swzf(sa,bestk); P.SB[j]=swzf(sb,bestk); P.SC[j]=swzf(sc,bestk);
  }
  for(int t=0;t<10;++t){
    P.TA[t]=swzf(P.A[4+t],bestk);
    P.TB[t]=swzf(P.B[4+t],bestk);
    P.TCc[t]=swzf(P.C[4+t],bestk);
  }
  return P;
}

constexpr Plan PL = make_plan();
static_assert(rank_of(PL.A,14)==14, "phase A map not bijective");
static_assert(rank_of(PL.B,14)==14, "phase B map not bijective");
static_assert(rank_of(PL.C,14)==14, "phase C map not bijective");

// ---------------- packed-f32 complex helpers ----------------
__device__ __forceinline__ v2f mkv(float a, float b){ v2f r; r[0]=a; r[1]=b; return r; }

__device__ __forceinline__ v2f pk_mul(v2f a, v2f b){
  v2f d; asm("v_pk_mul_f32 %0, %1, %2 op_sel:[0,0] op_sel_hi:[1,1]" : "=v"(d) : "v"(a), "v"(b)); return d;
}
__device__ __forceinline__ v2f pk_fma(v2f a, v2f b, v2f c){
  v2f d; asm("v_pk_fma_f32 %0, %1, %2, %3 op_sel:[0,0,0] op_sel_hi:[1,1,1]" : "=v"(d) : "v"(a), "v"(b), "v"(c)); return d;
}
__device__ __forceinline__ v2f pk_fma_swap1(v2f a, v2f b, v2f c){
  v2f d; asm("v_pk_fma_f32 %0, %1, %2, %3 op_sel:[0,1,0] op_sel_hi:[1,0,1]" : "=v"(d) : "v"(a), "v"(b), "v"(c)); return d;
}
__device__ __forceinline__ v2f cmul_pk(v2f uxx, v2f uyn, v2f s){ return pk_fma_swap1(uyn, s, pk_mul(uxx, s)); }
__device__ __forceinline__ v2f cfma_pk(v2f uxx, v2f uyn, v2f s, v2f acc){ return pk_fma_swap1(uyn, s, pk_fma(uxx, s, acc)); }

__device__ __forceinline__ float2 cmulf(float2 a, float2 b){
  return make_float2(a.x*b.x - a.y*b.y, a.x*b.y + a.y*b.x);
}
__device__ __forceinline__ v2f sel2(bool c, v2f x, v2f y){ v2f r; r[0]=c?x[0]:y[0]; r[1]=c?x[1]:y[1]; return r; }

// gate constants: packed (x,x) / (-y,y) per entry, rows U00,U01,U10,U11
struct GC { v2f u00x,u00n,u01x,u01n,u10x,u10n,u11x,u11n; };
__device__ __forceinline__ GC load_gc(const v2f* __restrict__ g){
  GC c{g[0],g[1],g[2],g[3],g[4],g[5],g[6],g[7]}; return c;
}

// lane exchange: KIND 0=DPP(ctrl), 1=ds_swizzle(ctrl), 2=ds_bpermute(^32)
template<int KIND, int CTRL>
__device__ __forceinline__ v2f xchg(v2f v, int bpa){
  int x0=__float_as_int(v[0]), x1=__float_as_int(v[1]);
  int y0, y1;
  if constexpr (KIND==0){
    y0=__builtin_amdgcn_update_dpp(0,x0,CTRL,0xF,0xF,true);
    y1=__builtin_amdgcn_update_dpp(0,x1,CTRL,0xF,0xF,true);
  } else if constexpr (KIND==1){
    y0=__builtin_amdgcn_ds_swizzle(x0,CTRL);
    y1=__builtin_amdgcn_ds_swizzle(x1,CTRL);
  } else {
    y0=__builtin_amdgcn_ds_bpermute(bpa,x0);
    y1=__builtin_amdgcn_ds_bpermute(bpa,x1);
  }
  v2f r; r[0]=__int_as_float(y0); r[1]=__int_as_float(y1); return r;
}

// gate along register bit BIT; eps swaps roles of the two sides
template<int BIT>
__device__ __forceinline__ void reg_gate(v2f (&a)[16], const GC& c, bool eps){
  v2f m00x=sel2(eps,c.u11x,c.u00x), m00n=sel2(eps,c.u11n,c.u00n);
  v2f m01x=sel2(eps,c.u10x,c.u01x), m01n=sel2(eps,c.u10n,c.u01n);
  v2f m10x=sel2(eps,c.u01x,c.u10x), m10n=sel2(eps,c.u01n,c.u10n);
  v2f m11x=sel2(eps,c.u00x,c.u11x), m11n=sel2(eps,c.u00n,c.u11n);
#pragma unroll
  for(int v=0; v<16; ++v){
    if(!((v>>BIT)&1)){
      int w = v | (1<<BIT);
      v2f a0=a[v], a1=a[w];
      a[v] = cfma_pk(m01x,m01n,a1, cmul_pk(m00x,m00n,a0));
      a[w] = cfma_pk(m11x,m11n,a1, cmul_pk(m10x,m10n,a0));
    }
  }
}

// gate along a lane bit; sel = my physical-role bit (lane bit ^ runtime eps); PI4 = per-j parity
template<int KIND, int CTRL, unsigned PI4>
__device__ __forceinline__ void lane_gate(v2f (&a)[16], const GC& c, bool sel, int bpa){
  v2f kax0=sel2(sel,c.u11x,c.u00x), kan0=sel2(sel,c.u11n,c.u00n);
  v2f kbx0=sel2(sel,c.u10x,c.u01x), kbn0=sel2(sel,c.u10n,c.u01n);
  v2f kax1=sel2(sel,c.u00x,c.u11x), kan1=sel2(sel,c.u00n,c.u11n);
  v2f kbx1=sel2(sel,c.u01x,c.u10x), kbn1=sel2(sel,c.u01n,c.u10n);
#pragma unroll
  for(int j=0;j<16;++j){
    v2f th = xchg<KIND,CTRL>(a[j], bpa);
    bool pi = (__builtin_popcount(PI4 & (unsigned)j) & 1) != 0;   // folds per unrolled j
    v2f kax = pi?kax1:kax0, kan = pi?kan1:kan0;
    v2f kbx = pi?kbx1:kbx0, kbn = pi?kbn1:kbn0;
    a[j] = cfma_pk(kbx,kbn,th, cmul_pk(kax,kan,a[j]));
  }
}

__device__ __forceinline__ unsigned base10(unsigned tid, const unsigned (&tc)[10]){
  unsigned s=0;
#pragma unroll
  for(int t=0;t<10;++t) s ^= tc[t] & (0u - ((tid>>t)&1u));
  return s;
}

// ---------------- kernels ----------------
__global__ void prep_gates(const float* __restrict__ prm, float* __restrict__ wsf){
  int t = threadIdx.x;
  if(t >= 2*NQ) return;
  int l = 1 + t/NQ, q = t % NQ;
  float ax=prm[(l*NQ+q)*3+0], ay=prm[(l*NQ+q)*3+1], az=prm[(l*NQ+q)*3+2];
  float cx,sx,cy,sy,cz,sz;
  sincosf(0.5f*ax,&sx,&cx); sincosf(0.5f*ay,&sy,&cy); sincosf(0.5f*az,&sz,&cz);
  float2 M00=make_float2(cy*cx, sy*sx),  M01=make_float2(-sy*cx,-cy*sx);
  float2 M10=make_float2(sy*cx,-cy*sx),  M11=make_float2(cy*cx,-sy*sx);
  float2 ez =make_float2(cz,-sz), ezc=make_float2(cz,sz);
  float2 U00=cmulf(ez,M00), U01=cmulf(ez,M01), U10=cmulf(ezc,M10), U11=cmulf(ezc,M11);
  float* o = wsf + t*16;
  o[0]=U00.x; o[1]=U00.x; o[2]=-U00.y; o[3]=U00.y;
  o[4]=U01.x; o[5]=U01.x; o[6]=-U01.y; o[7]=U01.y;
  o[8]=U10.x; o[9]=U10.x; o[10]=-U10.y; o[11]=U10.y;
  o[12]=U11.x; o[13]=U11.x; o[14]=-U11.y; o[15]=U11.y;
}

__global__ __launch_bounds__(BLOCK, 4) void qsim_kernel(
    const float* __restrict__ x,
    const float* __restrict__ prm,
    const v2f*  __restrict__ gw,     // 28 gates x 8 v2f in workspace
    float* __restrict__ out)
{
  __shared__ v2f    st[NSTATES];       // 128 KiB state
  __shared__ float2 l0c[NQ][2];        // layer-0 |0>-columns
  __shared__ float  red[NWAVES][NQ];

  const int b   = blockIdx.x;
  const unsigned tid = threadIdx.x;
  const int bpa = (int)((((tid&63u)^32u)<<2));

  // ---- layer-0 columns (x-dependent) ----
  if(tid < NQ){
    int q = tid;
    float ax = prm[q*3+0] + x[b*NQ+q];
    float ay = prm[q*3+1], az = prm[q*3+2];
    float cx,sx,cy,sy,cz,sz;
    sincosf(0.5f*ax,&sx,&cx); sincosf(0.5f*ay,&sy,&cy); sincosf(0.5f*az,&sz,&cz);
    l0c[q][0] = cmulf(make_float2(cz,-sz), make_float2(cy*cx,  sy*sx));   // U00
    l0c[q][1] = cmulf(make_float2(cz, sz), make_float2(sy*cx, -cy*sx));   // U10
  }
  __syncthreads();

  // ---- init: product state |psi0> = layer-0 applied to |0...0> ----
  {
    float2 Pk = l0c[0][(tid>>9)&1];
#pragma unroll
    for(int q=1;q<10;++q) Pk = cmulf(Pk, l0c[q][(tid>>(9-q))&1]);
    float2 t2[2], t4[4];
    t2[0]=cmulf(Pk,l0c[10][0]); t2[1]=cmulf(Pk,l0c[10][1]);
#pragma unroll
    for(int i=0;i<2;++i){ t4[2*i]=cmulf(t2[i],l0c[11][0]); t4[2*i+1]=cmulf(t2[i],l0c[11][1]); }
#pragma unroll
    for(int j=0;j<16;++j){
      float2 v = cmulf(cmulf(t4[j>>2], l0c[12][(j>>1)&1]), l0c[13][j&1]);
      unsigned s = (tid<<4) | (unsigned)j;
      unsigned slot = s ^ ((s>>PL.K)&31u);
      st[slot] = mkv(v.x, v.y);
    }
  }
  __syncthreads();

  // ---- phase A: layer-1, 4 reg + 6 lane gates (all same-layer: clean) ----
  {
    unsigned sb = base10(tid, PL.TA);
    v2f a[16];
#pragma unroll
    for(int j=0;j<16;++j) a[j] = st[sb ^ PL.SA[j]];
    reg_gate<0>(a, load_gc(gw+0*8), false);
    reg_gate<1>(a, load_gc(gw+1*8), false);
    reg_gate<2>(a, load_gc(gw+2*8), false);
    reg_gate<3>(a, load_gc(gw+3*8), false);
    lane_gate<0,0xB1,  0u>(a, load_gc(gw+4*8), (tid&1)!=0,  bpa);
    lane_gate<0,0x4E,  0u>(a, load_gc(gw+5*8), (tid&2)!=0,  bpa);
    lane_gate<1,0x101F,0u>(a, load_gc(gw+6*8), (tid&4)!=0,  bpa);
    lane_gate<1,0x201F,0u>(a, load_gc(gw+7*8), (tid&8)!=0,  bpa);
    lane_gate<1,0x401F,0u>(a, load_gc(gw+8*8), (tid&16)!=0, bpa);
    lane_gate<2,0,     0u>(a, load_gc(gw+9*8), (tid&32)!=0, bpa);
#pragma unroll
    for(int j=0;j<16;++j) st[sb ^ PL.SA[j]] = a[j];
  }
  __syncthreads();

  // ---- phase B: layer-1 leftover (reg, runtime eps) + 6 layer-2 lane gates (compile-time pi) ----
  {
    unsigned sb = base10(tid, PL.TB);
    v2f a[16];
#pragma unroll
    for(int j=0;j<16;++j) a[j] = st[sb ^ PL.SB[j]];
    reg_gate<0>(a, load_gc(gw+PL.BregGi[0]*8), (__builtin_popcount(PL.BregEps[0]&tid)&1)!=0);
    reg_gate<1>(a, load_gc(gw+PL.BregGi[1]*8), (__builtin_popcount(PL.BregEps[1]&tid)&1)!=0);
    reg_gate<2>(a, load_gc(gw+PL.BregGi[2]*8), (__builtin_popcount(PL.BregEps[2]&tid)&1)!=0);
    reg_gate<3>(a, load_gc(gw+PL.BregGi[3]*8), (__builtin_popcount(PL.BregEps[3]&tid)&1)!=0);
    lane_gate<0,0xB1,  PL.BlanePi4[0]>(a, load_gc(gw+PL.BlaneGi[0]*8), (tid&1)!=0,  bpa);
    lane_gate<0,0x4E,  PL.BlanePi4[1]>(a, load_gc(gw+PL.BlaneGi[1]*8), (tid&2)!=0,  bpa);
    lane_gate<1,0x101F,PL.BlanePi4[2]>(a, load_gc(gw+PL.BlaneGi[2]*8), (tid&4)!=0,  bpa);
    lane_gate<1,0x201F,PL.BlanePi4[3]>(a, load_gc(gw+PL.BlaneGi[3]*8), (tid&8)!=0,  bpa);
    lane_gate<1,0x401F,PL.BlanePi4[4]>(a, load_gc(gw+PL.BlaneGi[4]*8), (tid&16)!=0, bpa);
    lane_gate<2,0,     PL.BlanePi4[5]>(a, load_gc(gw+PL.BlaneGi[5]*8), (tid&32)!=0, bpa);
#pragma unroll
    for(int j=0;j<16;++j) st[sb ^ PL.SB[j]] = a[j];
  }
  __syncthreads();

  // ---- phase C: last 8 layer-2 gates, then expectation straight from registers ----
  {
    unsigned sb = base10(tid, PL.TCc);
    v2f a[16];
#pragma unroll
    for(int j=0;j<16;++j) a[j] = st[sb ^ PL.SC[j]];
    reg_gate<0>(a, load_gc(gw+PL.CregGi[0]*8), (__builtin_popcount(PL.CregEps[0]&tid)&1)!=0);
    reg_gate<1>(a, load_gc(gw+PL.CregGi[1]*8), (__builtin_popcount(PL.CregEps[1]&tid)&1)!=0);
    reg_gate<2>(a, load_gc(gw+PL.CregGi[2]*8), (__builtin_popcount(PL.CregEps[2]&tid)&1)!=0);
    reg_gate<3>(a, load_gc(gw+PL.CregGi[3]*8), (__builtin_popcount(PL.CregEps[3]&tid)&1)!=0);
    lane_gate<0,0xB1,  0u>(a, load_gc(gw+PL.ClaneGi[0]*8),
        (((tid&1u)!=0) != ((__builtin_popcount(PL.ClaneEps[0]&tid)&1)!=0)), bpa);
    lane_gate<0,0x4E,  0u>(a, load_gc(gw+PL.ClaneGi[1]*8),
        (((tid&2u)!=0) != ((__builtin_popcount(PL.ClaneEps[1]&tid)&1)!=0)), bpa);
    lane_gate<1,0x101F,0u>(a, load_gc(gw+PL.ClaneGi[2]*8),
        (((tid&4u)!=0) != ((__builtin_popcount(PL.ClaneEps[2]&tid)&1)!=0)), bpa);
    lane_gate<1,0x201F,0u>(a, load_gc(gw+PL.ClaneGi[3]*8),
        (((tid&8u)!=0) != ((__builtin_popcount(PL.ClaneEps[3]&tid)&1)!=0)), bpa);

    // expectation values from registers
    float acc[NQ];
#pragma unroll
    for(int w=0;w<NQ;++w) acc[w]=0.f;
#pragma unroll
    for(int j=0;j<16;++j){
      float p = a[j][0]*a[j][0] + a[j][1]*a[j][1];
#pragma unroll
      for(int w=0;w<NQ;++w){
        if(__builtin_popcount(PL.EJ4[w] & (unsigned)j) & 1) acc[w]-=p; else acc[w]+=p;
      }
    }
    const int lane = tid & 63, wave = tid >> 6;
#pragma unroll
    for(int w=0;w<NQ;++w){
      float v = (__builtin_popcount(PL.ET[w]&tid)&1) ? -acc[w] : acc[w];
#pragma unroll
      for(int off=32; off>0; off>>=1) v += __shfl_down(v, off, 64);
      if(lane==0) red[wave][w]=v;
    }
    __syncthreads();
    if(tid < NQ){
      float s=0.f;
#pragma unroll
      for(int wv=0; wv<NWAVES; ++wv) s += red[wv][tid];
      out[b*NQ + tid] = s;
    }
  }
}

}  // namespace

extern "C" void kernel_launch(void* const* d_in, const int* in_sizes, int n_in,
                              void* d_out, int out_size, void* d_ws, size_t ws_size,
                              hipStream_t stream) {
  const float* x   = (const float*)d_in[0];   // (batch, 14) f32
  const float* prm = (const float*)d_in[1];   // (3, 14, 3) f32
  float* out = (float*)d_out;                 // (batch, 14) f32
  const int batch = in_sizes[0] / NQ;
  prep_gates<<<1, 64, 0, stream>>>(prm, (float*)d_ws);
  qsim_kernel<<<batch, BLOCK, 0, stream>>>(x, prm, (const v2f*)d_ws, out);
}